// Round 4
// baseline (354.690 us; speedup 1.0000x reference)
//
#include <hip/hip_runtime.h>

#define B_ 4
#define C_ 256
#define H_ 64
#define W_ 64
#define HW_ 4096
#define CO_ 256
#define NPX_ 16384
#define GN_EPS_ 1e-5f

typedef float f32x4 __attribute__((ext_vector_type(4)));
typedef short s16x8 __attribute__((ext_vector_type(8)));

__device__ __forceinline__ short f2bf(float f) {
    union { float f; unsigned u; } v; v.f = f;
    unsigned r = (v.u + 0x7FFFu + ((v.u >> 16) & 1u)) >> 16;
    return (short)(r & 0xFFFFu);
}

// ---------------- K0: w[oc][c][kk] -> wT[kk][oc][c] in bf16 ----------------
__global__ void k_prep_w(const float* __restrict__ w, short* __restrict__ wT) {
    int oc = blockIdx.x, c = threadIdx.x;
    const float* src = w + (oc * 256 + c) * 9;
    float v[9];
#pragma unroll
    for (int t = 0; t < 9; ++t) v[t] = src[t];
#pragma unroll
    for (int t = 0; t < 9; ++t) wT[(t * 256 + oc) * 256 + c] = f2bf(v[t]);
}

// ---------------- K1: offset conv partials (proven) ----------------
__global__ void k_offconv(const float* __restrict__ x, const float* __restrict__ w_off,
                          float* __restrict__ part) {
    int p  = blockIdx.x * 256 + threadIdx.x;
    int b  = p >> 12;
    int hw = p & 4095;
    int h  = hw >> 6;
    int w  = hw & 63;
    int c0 = blockIdx.y * 32;

    float acc[27];
#pragma unroll
    for (int o = 0; o < 27; ++o) acc[o] = 0.f;

    const float* xb = x + (b * C_ + c0) * HW_;
    for (int c = 0; c < 32; ++c) {
        const float* xc = xb + c * HW_;
        const float* wc = w_off + (c0 + c) * 9;
        float v[9];
#pragma unroll
        for (int t = 0; t < 9; ++t) {
            int ki = t / 3, kj = t % 3;
            int yy = h + ki - 1, xx = w + kj - 1;
            bool ok = (yy >= 0) & (yy < H_) & (xx >= 0) & (xx < W_);
            v[t] = ok ? xc[yy * W_ + xx] : 0.f;
        }
#pragma unroll
        for (int o = 0; o < 27; ++o) {
            const float* wo = wc + o * 2304;
#pragma unroll
            for (int t = 0; t < 9; ++t) acc[o] += v[t] * wo[t];
        }
    }
    float* pp = part + blockIdx.y * (27 * NPX_) + p;
#pragma unroll
    for (int o = 0; o < 27; ++o) pp[o * NPX_] = acc[o];
}

// ---------------- K1b: reduce partials + bias ----------------
__global__ void k_offreduce(const float* __restrict__ part, const float* __restrict__ b_off,
                            float* __restrict__ off) {
    int idx = blockIdx.x * 256 + threadIdx.x;
    int oc  = idx >> 14;
    float s = b_off[oc];
#pragma unroll
    for (int j = 0; j < 8; ++j) s += part[j * (27 * NPX_) + idx];
    off[idx] = s;
}

// ---------------- K2a: bilinear sample -> val[kk][px][c] bf16 ----------------
// grid (64, 16): bx = 256-px tile, by = 16-channel chunk. 256 threads, no barriers.
__global__ void k_sample(const float* __restrict__ x, const float* __restrict__ off,
                         short* __restrict__ val) {
    int p  = blockIdx.x * 256 + threadIdx.x;     // global pixel
    int b  = p >> 12;
    int hw = p & 4095;
    int h  = hw >> 6;
    int wc = hw & 63;
    int c0 = blockIdx.y * 16;

    const float* xb = x + (b * C_ + c0) * HW_;

#pragma unroll 1
    for (int kk = 0; kk < 9; ++kk) {
        int ki = kk / 3, kj = kk % 3;
        float dy = off[(2 * kk) * NPX_ + p];
        float dx = off[(2 * kk + 1) * NPX_ + p];
        float mk = off[(18 + kk) * NPX_ + p];
        mk = 1.f / (1.f + __expf(-mk));

        float py  = (float)(h + ki - 1) + dy;
        float pxf = (float)(wc + kj - 1) + dx;
        float y0f = floorf(py), x0f = floorf(pxf);
        float ly = py - y0f, lx = pxf - x0f;
        int y0 = (int)y0f, x0 = (int)x0f;
        int y1 = y0 + 1, x1 = x0 + 1;

        float w00 = (1.f - ly) * (1.f - lx) * mk;
        float w01 = (1.f - ly) * lx * mk;
        float w10 = ly * (1.f - lx) * mk;
        float w11 = ly * lx * mk;
        bool vy0 = (y0 >= 0) & (y0 < H_);
        bool vy1 = (y1 >= 0) & (y1 < H_);
        bool vx0 = (x0 >= 0) & (x0 < W_);
        bool vx1 = (x1 >= 0) & (x1 < W_);
        if (!(vy0 & vx0)) w00 = 0.f;
        if (!(vy0 & vx1)) w01 = 0.f;
        if (!(vy1 & vx0)) w10 = 0.f;
        if (!(vy1 & vx1)) w11 = 0.f;
        int cy0 = min(max(y0, 0), H_ - 1), cy1 = min(max(y1, 0), H_ - 1);
        int cx0 = min(max(x0, 0), W_ - 1), cx1 = min(max(x1, 0), W_ - 1);
        int o00 = cy0 * W_ + cx0, o01 = cy0 * W_ + cx1;
        int o10 = cy1 * W_ + cx0, o11 = cy1 * W_ + cx1;

        short* dst = val + (kk * NPX_ + p) * 256 + c0;
        s16x8 pk;
#pragma unroll
        for (int cc = 0; cc < 16; ++cc) {
            const float* xc = xb + cc * HW_;
            float g = w00 * xc[o00] + w01 * xc[o01] + w10 * xc[o10] + w11 * xc[o11];
            pk[cc & 7] = f2bf(g);
            if ((cc & 7) == 7)
                *reinterpret_cast<s16x8*>(dst + (cc & ~7)) = pk;
        }
    }
}

// ---------------- K2b: dense MFMA GEMM (no LDS, no barriers) ----------------
// grid 512: bid = ochalf*256 + pxt. Block: 64 px x 128 oc, 256 threads = 4 waves.
// Wave w: px half (w>>1)*32, oc slab (w&1)*64.
// A = val[kk][px][c] bf16, B = wT[kk][oc][c] bf16, both straight from global/L2.
__global__ void k_gemm(const short* __restrict__ val, const short* __restrict__ wT,
                       const float* __restrict__ bias, float* __restrict__ out,
                       float* __restrict__ gnpart) {
    __shared__ float red[8];

    int tid  = threadIdx.x;
    int lane = tid & 63;
    int wv   = tid >> 6;

    int pxt    = blockIdx.x & 255;
    int ochalf = blockIdx.x >> 8;

    int px0 = pxt * 64;
    int b   = px0 >> 12;
    int hw0 = px0 & 4095;

    int pxh  = (wv >> 1) * 32;
    int oc0  = ochalf * 128 + (wv & 1) * 64;

    int lm = lane & 15;          // M/N row within fragment
    int lk = (lane >> 4) * 8;    // K sub-offset

    f32x4 acc[2][4];
#pragma unroll
    for (int i = 0; i < 2; ++i)
#pragma unroll
        for (int j = 0; j < 4; ++j) acc[i][j] = (f32x4)0.f;

    const short* aBase = val + (long)(px0 + pxh + lm) * 256 + lk;
    const short* bBase = wT + (oc0 + lm) * 256 + lk;

#pragma unroll 1
    for (int kk = 0; kk < 9; ++kk) {
        const short* aK = aBase + (long)kk * (NPX_ * 256);
        const short* bK = bBase + kk * 65536;
#pragma unroll
        for (int ks = 0; ks < 8; ++ks) {
            int c = ks * 32;
            s16x8 a[2], bf[4];
#pragma unroll
            for (int mt = 0; mt < 2; ++mt)
                a[mt] = *reinterpret_cast<const s16x8*>(aK + mt * 16 * 256 + c);
#pragma unroll
            for (int nt = 0; nt < 4; ++nt)
                bf[nt] = *reinterpret_cast<const s16x8*>(bK + nt * 16 * 256 + c);
#pragma unroll
            for (int mt = 0; mt < 2; ++mt)
#pragma unroll
                for (int nt = 0; nt < 4; ++nt)
                    acc[mt][nt] = __builtin_amdgcn_mfma_f32_16x16x32_bf16(
                        a[mt], bf[nt], acc[mt][nt], 0, 0, 0);
        }
    }

    // epilogue: bias + store + GN partial
    float s = 0.f, sq = 0.f;
#pragma unroll
    for (int nt = 0; nt < 4; ++nt) {
        int oc = oc0 + nt * 16 + lm;
        float bv = bias[oc];
        float* orow = out + (b * CO_ + oc) * HW_ + hw0 + pxh;
#pragma unroll
        for (int mt = 0; mt < 2; ++mt) {
            f32x4 r = acc[mt][nt];
            r.x += bv; r.y += bv; r.z += bv; r.w += bv;
            s  += r.x + r.y + r.z + r.w;
            sq += r.x * r.x + r.y * r.y + r.z * r.z + r.w * r.w;
            *reinterpret_cast<f32x4*>(orow + mt * 16 + (lane >> 4) * 4) = r;
        }
    }
#pragma unroll
    for (int o = 32; o > 0; o >>= 1) {
        s  += __shfl_down(s, o, 64);
        sq += __shfl_down(sq, o, 64);
    }
    if (lane == 0) { red[wv * 2] = s; red[wv * 2 + 1] = sq; }
    __syncthreads();
    if (tid == 0) {
        float S = 0.f, SQ = 0.f;
#pragma unroll
        for (int k = 0; k < 4; ++k) { S += red[k * 2]; SQ += red[k * 2 + 1]; }
        gnpart[blockIdx.x * 2]     = S;
        gnpart[blockIdx.x * 2 + 1] = SQ;
    }
}

// ---------------- K4: finalize stats. grid 4 (batch), 64 threads ----------------
// batch b's blocks: pxt in [b*64, b*64+64), ochalf in {0,1}
__global__ void k_gn_stats(const float* __restrict__ part, float* __restrict__ stats) {
    int b = blockIdx.x;
    const float2* pp = reinterpret_cast<const float2*>(part);
    float2 v0 = pp[b * 64 + threadIdx.x];           // ochalf 0
    float2 v1 = pp[256 + b * 64 + threadIdx.x];     // ochalf 1
    float s = v0.x + v1.x, sq = v0.y + v1.y;
#pragma unroll
    for (int o = 32; o > 0; o >>= 1) {
        s  += __shfl_down(s, o, 64);
        sq += __shfl_down(sq, o, 64);
    }
    if (threadIdx.x == 0) {
        const float n = (float)(CO_ * HW_);
        float mean = s / n;
        float var  = sq / n - mean * mean;
        stats[b * 2] = mean;
        stats[b * 2 + 1] = rsqrtf(var + GN_EPS_);
    }
}

// ---------------- K5: normalize + affine + relu ----------------
__global__ void k_gn_apply(float* __restrict__ y, const float* __restrict__ stats,
                           const float* __restrict__ gamma, const float* __restrict__ beta) {
    int e4 = blockIdx.x * 256 + threadIdx.x;
    int b  = e4 >> 18;
    int oc = (e4 >> 10) & 255;
    float mean = stats[b * 2], rstd = stats[b * 2 + 1];
    float g  = gamma[oc] * rstd;
    float bb = beta[oc] - mean * g;
    float4* p = reinterpret_cast<float4*>(y);
    float4 v = p[e4];
    v.x = fmaxf(v.x * g + bb, 0.f);
    v.y = fmaxf(v.y * g + bb, 0.f);
    v.z = fmaxf(v.z * g + bb, 0.f);
    v.w = fmaxf(v.w * g + bb, 0.f);
    p[e4] = v;
}

extern "C" void kernel_launch(void* const* d_in, const int* in_sizes, int n_in,
                              void* d_out, int out_size, void* d_ws, size_t ws_size,
                              hipStream_t stream) {
    const float* x     = (const float*)d_in[0];
    const float* w_off = (const float*)d_in[1];
    const float* b_off = (const float*)d_in[2];
    const float* w     = (const float*)d_in[3];
    const float* bias  = (const float*)d_in[4];
    const float* gamma = (const float*)d_in[5];
    const float* beta  = (const float*)d_in[6];
    float* out = (float*)d_out;

    // ws layout: [off 1.77MB][wT 1.18MB][gnpart+stats][val 75.5MB]
    // part1 (14.2MB, dead after k_offreduce) aliases the val region.
    float* Wp     = (float*)d_ws;
    float* off    = Wp;                              // 27*16384 floats
    short* wT     = (short*)(off + 27 * NPX_);       // 9*256*256 shorts
    float* gnpart = (float*)(wT + 9 * 256 * 256);    // 1024 floats
    float* stats  = gnpart + 1024;                   // 8 floats
    short* val    = (short*)(stats + 8);             // 9*16384*256 shorts
    float* part1  = (float*)val;                     // aliased scratch

    k_prep_w<<<256, 256, 0, stream>>>(w, wT);
    k_offconv<<<dim3(64, 8), 256, 0, stream>>>(x, w_off, part1);
    k_offreduce<<<1728, 256, 0, stream>>>(part1, b_off, off);
    k_sample<<<dim3(64, 16), 256, 0, stream>>>(x, off, val);
    k_gemm<<<512, 256, 0, stream>>>(val, wT, bias, out, gnpart);
    k_gn_stats<<<4, 64, 0, stream>>>(gnpart, stats);
    k_gn_apply<<<4096, 256, 0, stream>>>(out, stats, gamma, beta);
}

// Round 5
// 283.306 us; speedup vs baseline: 1.2520x; 1.2520x over previous
//
#include <hip/hip_runtime.h>

#define B_ 4
#define C_ 256
#define H_ 64
#define W_ 64
#define HW_ 4096
#define CO_ 256
#define NPX_ 16384
#define GN_EPS_ 1e-5f

typedef float f32x4 __attribute__((ext_vector_type(4)));
typedef short s16x8 __attribute__((ext_vector_type(8)));

__device__ __forceinline__ short f2bf(float f) {
    union { float f; unsigned u; } v; v.f = f;
    unsigned r = (v.u + 0x7FFFu + ((v.u >> 16) & 1u)) >> 16;
    return (short)(r & 0xFFFFu);
}
__device__ __forceinline__ float bf2f(short s) {
    union { unsigned u; float f; } v; v.u = ((unsigned)s & 0xFFFFu) << 16;
    return v.f;
}

// ---------------- K0: w[oc][c][kk] -> wT[kk][oc][c] in bf16 ----------------
__global__ void k_prep_w(const float* __restrict__ w, short* __restrict__ wT) {
    int oc = blockIdx.x, c = threadIdx.x;
    const float* src = w + (oc * 256 + c) * 9;
    float v[9];
#pragma unroll
    for (int t = 0; t < 9; ++t) v[t] = src[t];
#pragma unroll
    for (int t = 0; t < 9; ++t) wT[(t * 256 + oc) * 256 + c] = f2bf(v[t]);
}

// ---------------- K0b: x[b][c][hw] f32 -> xT[b][hw][c] bf16 ----------------
// grid 1024: (bx&255)=64-px tile, (bx>>8)=64-c chunk. 256 threads. LDS 64x72 shorts.
__global__ void k_xpose(const float* __restrict__ x, short* __restrict__ xT) {
    __shared__ short T[64 * 72];          // row stride 72 to break bank conflicts

    int bx  = blockIdx.x;
    int px0 = (bx & 255) * 64;
    int c0  = (bx >> 8) * 64;
    int b   = px0 >> 12;
    int hw0 = px0 & 4095;

    int t  = threadIdx.x;
    int cl = t & 63;                      // channel row
    int q  = t >> 6;                      // 0..3

    const float4* src = reinterpret_cast<const float4*>(
        x + (long)(b * 256 + c0 + cl) * 4096 + hw0);
#pragma unroll
    for (int j = 0; j < 4; ++j) {
        float4 v = src[j * 4 + q];
        int pl = (j * 4 + q) * 4;
        T[(pl + 0) * 72 + cl] = f2bf(v.x);
        T[(pl + 1) * 72 + cl] = f2bf(v.y);
        T[(pl + 2) * 72 + cl] = f2bf(v.z);
        T[(pl + 3) * 72 + cl] = f2bf(v.w);
    }
    __syncthreads();

    int pl = t >> 2;                      // 0..63
    int s  = t & 3;                       // 16-c segment
    short* dst = xT + (long)(px0 + pl) * 256 + c0 + s * 16;
    s16x8 a = *reinterpret_cast<const s16x8*>(&T[pl * 72 + s * 16]);
    s16x8 bseg = *reinterpret_cast<const s16x8*>(&T[pl * 72 + s * 16 + 8]);
    *reinterpret_cast<s16x8*>(dst)     = a;
    *reinterpret_cast<s16x8*>(dst + 8) = bseg;
}

// ---------------- K1: offset conv partials (unchanged) ----------------
__global__ void k_offconv(const float* __restrict__ x, const float* __restrict__ w_off,
                          float* __restrict__ part) {
    int p  = blockIdx.x * 256 + threadIdx.x;
    int b  = p >> 12;
    int hw = p & 4095;
    int h  = hw >> 6;
    int w  = hw & 63;
    int c0 = blockIdx.y * 32;

    float acc[27];
#pragma unroll
    for (int o = 0; o < 27; ++o) acc[o] = 0.f;

    const float* xb = x + (b * C_ + c0) * HW_;
    for (int c = 0; c < 32; ++c) {
        const float* xc = xb + c * HW_;
        const float* wc = w_off + (c0 + c) * 9;
        float v[9];
#pragma unroll
        for (int t = 0; t < 9; ++t) {
            int ki = t / 3, kj = t % 3;
            int yy = h + ki - 1, xx = w + kj - 1;
            bool ok = (yy >= 0) & (yy < H_) & (xx >= 0) & (xx < W_);
            v[t] = ok ? xc[yy * W_ + xx] : 0.f;
        }
#pragma unroll
        for (int o = 0; o < 27; ++o) {
            const float* wo = wc + o * 2304;
#pragma unroll
            for (int t = 0; t < 9; ++t) acc[o] += v[t] * wo[t];
        }
    }
    float* pp = part + blockIdx.y * (27 * NPX_) + p;
#pragma unroll
    for (int o = 0; o < 27; ++o) pp[o * NPX_] = acc[o];
}

// ---------------- K1b: reduce partials + bias ----------------
__global__ void k_offreduce(const float* __restrict__ part, const float* __restrict__ b_off,
                            float* __restrict__ off) {
    int idx = blockIdx.x * 256 + threadIdx.x;
    int oc  = idx >> 14;
    float s = b_off[oc];
#pragma unroll
    for (int j = 0; j < 8; ++j) s += part[j * (27 * NPX_) + idx];
    off[idx] = s;
}

// ---------------- K2a: row-blend sample -> val[kk][cb][px][32c] bf16 ----------------
// grid 512 (32-px tiles), 256 threads. Half-wave (32 lanes) = one px, lanes cover 256 c.
__global__ void k_sample(const short* __restrict__ xT, const float* __restrict__ off,
                         short* __restrict__ val) {
    int tid = threadIdx.x;
    int l32 = tid & 31;
    int pxi = tid >> 5;                   // 0..7
    int px0 = blockIdx.x * 32;

    int cb = l32 >> 2;                    // 0..7
    int cw = (l32 & 3) * 8;               // 0,8,16,24

#pragma unroll 1
    for (int kk = 0; kk < 9; ++kk) {
        int ki = kk / 3, kj = kk % 3;
#pragma unroll 1
        for (int it = 0; it < 4; ++it) {
            int p  = px0 + it * 8 + pxi;
            int b  = p >> 12;
            int hw = p & 4095;
            int h  = hw >> 6;
            int wc = hw & 63;

            float dy = off[(2 * kk) * NPX_ + p];
            float dx = off[(2 * kk + 1) * NPX_ + p];
            float mk = off[(18 + kk) * NPX_ + p];
            mk = 1.f / (1.f + __expf(-mk));

            float py  = (float)(h + ki - 1) + dy;
            float pxf = (float)(wc + kj - 1) + dx;
            float y0f = floorf(py), x0f = floorf(pxf);
            float ly = py - y0f, lx = pxf - x0f;
            int y0 = (int)y0f, x0 = (int)x0f;
            int y1 = y0 + 1, x1 = x0 + 1;

            float w00 = (1.f - ly) * (1.f - lx) * mk;
            float w01 = (1.f - ly) * lx * mk;
            float w10 = ly * (1.f - lx) * mk;
            float w11 = ly * lx * mk;
            bool vy0 = (y0 >= 0) & (y0 < H_);
            bool vy1 = (y1 >= 0) & (y1 < H_);
            bool vx0 = (x0 >= 0) & (x0 < W_);
            bool vx1 = (x1 >= 0) & (x1 < W_);
            if (!(vy0 & vx0)) w00 = 0.f;
            if (!(vy0 & vx1)) w01 = 0.f;
            if (!(vy1 & vx0)) w10 = 0.f;
            if (!(vy1 & vx1)) w11 = 0.f;
            int cy0 = min(max(y0, 0), H_ - 1), cy1 = min(max(y1, 0), H_ - 1);
            int cx0 = min(max(x0, 0), W_ - 1), cx1 = min(max(x1, 0), W_ - 1);

            long rb = (long)b * 4096;
            const short* xrow = xT + l32 * 8;
            s16x8 r00 = *reinterpret_cast<const s16x8*>(xrow + (rb + cy0 * 64 + cx0) * 256);
            s16x8 r01 = *reinterpret_cast<const s16x8*>(xrow + (rb + cy0 * 64 + cx1) * 256);
            s16x8 r10 = *reinterpret_cast<const s16x8*>(xrow + (rb + cy1 * 64 + cx0) * 256);
            s16x8 r11 = *reinterpret_cast<const s16x8*>(xrow + (rb + cy1 * 64 + cx1) * 256);

            s16x8 o8;
#pragma unroll
            for (int j = 0; j < 8; ++j) {
                float g = w00 * bf2f(r00[j]) + w01 * bf2f(r01[j])
                        + w10 * bf2f(r10[j]) + w11 * bf2f(r11[j]);
                o8[j] = f2bf(g);
            }
            *reinterpret_cast<s16x8*>(val + ((long)(kk * 8 + cb) * NPX_ + p) * 32 + cw) = o8;
        }
    }
}

// ---------------- K2b: dense MFMA GEMM ----------------
// grid 512: bid = ochalf*256 + pxt. 64 px x 128 oc per block, 4 waves.
__global__ void k_gemm(const short* __restrict__ val, const short* __restrict__ wT,
                       const float* __restrict__ bias, float* __restrict__ out,
                       float* __restrict__ gnpart) {
    __shared__ float red[8];

    int tid  = threadIdx.x;
    int lane = tid & 63;
    int wv   = tid >> 6;

    int pxt    = blockIdx.x & 255;
    int ochalf = blockIdx.x >> 8;

    int px0 = pxt * 64;
    int b   = px0 >> 12;
    int hw0 = px0 & 4095;

    int pxh  = (wv >> 1) * 32;
    int oc0  = ochalf * 128 + (wv & 1) * 64;

    int lm = lane & 15;
    int lk = (lane >> 4) * 8;             // 0,8,16,24 (c within 32-block)

    f32x4 acc[2][4];
#pragma unroll
    for (int i = 0; i < 2; ++i)
#pragma unroll
        for (int j = 0; j < 4; ++j) acc[i][j] = (f32x4)0.f;

    // val[kk][ks][px][32c]: addr = ((kk*8+ks)*NPX_ + px)*32 + cw
    const short* aBase = val + (long)(px0 + pxh + lm) * 32 + lk;
    const short* bBase = wT + (oc0 + lm) * 256 + lk;

#pragma unroll 1
    for (int kk = 0; kk < 9; ++kk) {
        const short* aK = aBase + (long)kk * 8 * NPX_ * 32;
        const short* bK = bBase + kk * 65536;
#pragma unroll
        for (int ks = 0; ks < 8; ++ks) {
            s16x8 a[2], bf[4];
#pragma unroll
            for (int mt = 0; mt < 2; ++mt)
                a[mt] = *reinterpret_cast<const s16x8*>(aK + (long)ks * NPX_ * 32 + mt * 16 * 32);
#pragma unroll
            for (int nt = 0; nt < 4; ++nt)
                bf[nt] = *reinterpret_cast<const s16x8*>(bK + nt * 16 * 256 + ks * 32);
#pragma unroll
            for (int mt = 0; mt < 2; ++mt)
#pragma unroll
                for (int nt = 0; nt < 4; ++nt)
                    acc[mt][nt] = __builtin_amdgcn_mfma_f32_16x16x32_bf16(
                        a[mt], bf[nt], acc[mt][nt], 0, 0, 0);
        }
    }

    float s = 0.f, sq = 0.f;
#pragma unroll
    for (int nt = 0; nt < 4; ++nt) {
        int oc = oc0 + nt * 16 + lm;
        float bv = bias[oc];
        float* orow = out + (b * CO_ + oc) * HW_ + hw0 + pxh;
#pragma unroll
        for (int mt = 0; mt < 2; ++mt) {
            f32x4 r = acc[mt][nt];
            r.x += bv; r.y += bv; r.z += bv; r.w += bv;
            s  += r.x + r.y + r.z + r.w;
            sq += r.x * r.x + r.y * r.y + r.z * r.z + r.w * r.w;
            *reinterpret_cast<f32x4*>(orow + mt * 16 + (lane >> 4) * 4) = r;
        }
    }
#pragma unroll
    for (int o = 32; o > 0; o >>= 1) {
        s  += __shfl_down(s, o, 64);
        sq += __shfl_down(sq, o, 64);
    }
    if (lane == 0) { red[wv * 2] = s; red[wv * 2 + 1] = sq; }
    __syncthreads();
    if (tid == 0) {
        float S = 0.f, SQ = 0.f;
#pragma unroll
        for (int k = 0; k < 4; ++k) { S += red[k * 2]; SQ += red[k * 2 + 1]; }
        gnpart[blockIdx.x * 2]     = S;
        gnpart[blockIdx.x * 2 + 1] = SQ;
    }
}

// ---------------- K4: finalize stats ----------------
__global__ void k_gn_stats(const float* __restrict__ part, float* __restrict__ stats) {
    int b = blockIdx.x;
    const float2* pp = reinterpret_cast<const float2*>(part);
    float2 v0 = pp[b * 64 + threadIdx.x];
    float2 v1 = pp[256 + b * 64 + threadIdx.x];
    float s = v0.x + v1.x, sq = v0.y + v1.y;
#pragma unroll
    for (int o = 32; o > 0; o >>= 1) {
        s  += __shfl_down(s, o, 64);
        sq += __shfl_down(sq, o, 64);
    }
    if (threadIdx.x == 0) {
        const float n = (float)(CO_ * HW_);
        float mean = s / n;
        float var  = sq / n - mean * mean;
        stats[b * 2] = mean;
        stats[b * 2 + 1] = rsqrtf(var + GN_EPS_);
    }
}

// ---------------- K5: normalize + affine + relu ----------------
__global__ void k_gn_apply(float* __restrict__ y, const float* __restrict__ stats,
                           const float* __restrict__ gamma, const float* __restrict__ beta) {
    int e4 = blockIdx.x * 256 + threadIdx.x;
    int b  = e4 >> 18;
    int oc = (e4 >> 10) & 255;
    float mean = stats[b * 2], rstd = stats[b * 2 + 1];
    float g  = gamma[oc] * rstd;
    float bb = beta[oc] - mean * g;
    float4* p = reinterpret_cast<float4*>(y);
    float4 v = p[e4];
    v.x = fmaxf(v.x * g + bb, 0.f);
    v.y = fmaxf(v.y * g + bb, 0.f);
    v.z = fmaxf(v.z * g + bb, 0.f);
    v.w = fmaxf(v.w * g + bb, 0.f);
    p[e4] = v;
}

extern "C" void kernel_launch(void* const* d_in, const int* in_sizes, int n_in,
                              void* d_out, int out_size, void* d_ws, size_t ws_size,
                              hipStream_t stream) {
    const float* x     = (const float*)d_in[0];
    const float* w_off = (const float*)d_in[1];
    const float* b_off = (const float*)d_in[2];
    const float* w     = (const float*)d_in[3];
    const float* bias  = (const float*)d_in[4];
    const float* gamma = (const float*)d_in[5];
    const float* beta  = (const float*)d_in[6];
    float* out = (float*)d_out;

    // ws: [off 1.77MB][wT 1.18MB][gnpart/stats][xT 8.39MB][val 75.5MB]
    // part1 (14.2MB, dead after k_offreduce) aliases val.
    float* Wp     = (float*)d_ws;
    float* off    = Wp;                               // 442368 floats
    short* wT     = (short*)(off + 27 * NPX_);        // 589824 shorts
    float* gnpart = (float*)(wT + 9 * 256 * 256);     // 1024 floats
    float* stats  = gnpart + 1024;                    // 8 floats
    short* xT     = (short*)(stats + 8);              // 4194304 shorts
    short* val    = xT + (long)NPX_ * 256;            // 9*8*16384*32 shorts
    float* part1  = (float*)val;

    k_prep_w<<<256, 256, 0, stream>>>(w, wT);
    k_xpose<<<1024, 256, 0, stream>>>(x, xT);
    k_offconv<<<dim3(64, 8), 256, 0, stream>>>(x, w_off, part1);
    k_offreduce<<<1728, 256, 0, stream>>>(part1, b_off, off);
    k_sample<<<512, 256, 0, stream>>>(xT, off, val);
    k_gemm<<<512, 256, 0, stream>>>(val, wT, bias, out, gnpart);
    k_gn_stats<<<4, 64, 0, stream>>>(gnpart, stats);
    k_gn_apply<<<4096, 256, 0, stream>>>(out, stats, gamma, beta);
}

// Round 6
// 254.677 us; speedup vs baseline: 1.3927x; 1.1124x over previous
//
#include <hip/hip_runtime.h>

#define B_ 4
#define C_ 256
#define H_ 64
#define W_ 64
#define HW_ 4096
#define CO_ 256
#define NPX_ 16384
#define GN_EPS_ 1e-5f

typedef float f32x4 __attribute__((ext_vector_type(4)));
typedef short s16x8 __attribute__((ext_vector_type(8)));

__device__ __forceinline__ short f2bf(float f) {
    union { float f; unsigned u; } v; v.f = f;
    unsigned r = (v.u + 0x7FFFu + ((v.u >> 16) & 1u)) >> 16;
    return (short)(r & 0xFFFFu);
}
__device__ __forceinline__ float bf2f(short s) {
    union { unsigned u; float f; } v; v.u = ((unsigned)s & 0xFFFFu) << 16;
    return v.f;
}

// ---------------- K0: w[oc][c][kk] -> wT[kk][oc][c] bf16 ----------------
__global__ void k_prep_w(const float* __restrict__ w, short* __restrict__ wT) {
    int oc = blockIdx.x, c = threadIdx.x;
    const float* src = w + (oc * 256 + c) * 9;
    float v[9];
#pragma unroll
    for (int t = 0; t < 9; ++t) v[t] = src[t];
#pragma unroll
    for (int t = 0; t < 9; ++t) wT[(t * 256 + oc) * 256 + c] = f2bf(v[t]);
}

// ---------------- K0a: w_off[27][256][9] -> wOffT[kk][32][256] bf16 (rows 27..31 zero) ----
__global__ void k_prep_woff(const float* __restrict__ w_off, short* __restrict__ wOffT) {
    int o = blockIdx.x;      // 0..31
    int c = threadIdx.x;     // 0..255
    if (o < 27) {
        const float* src = w_off + (o * 256 + c) * 9;
#pragma unroll
        for (int t = 0; t < 9; ++t)
            wOffT[(t * 32 + o) * 256 + c] = f2bf(src[t]);
    } else {
#pragma unroll
        for (int t = 0; t < 9; ++t)
            wOffT[(t * 32 + o) * 256 + c] = 0;
    }
}

// ---------------- K0b: x[b][c][hw] f32 -> xT[b][hw][c] bf16 ----------------
__global__ void k_xpose(const float* __restrict__ x, short* __restrict__ xT) {
    __shared__ short T[64 * 72];

    int bx  = blockIdx.x;
    int px0 = (bx & 255) * 64;
    int c0  = (bx >> 8) * 64;
    int b   = px0 >> 12;
    int hw0 = px0 & 4095;

    int t  = threadIdx.x;
    int cl = t & 63;
    int q  = t >> 6;

    const float4* src = reinterpret_cast<const float4*>(
        x + (long)(b * 256 + c0 + cl) * 4096 + hw0);
#pragma unroll
    for (int j = 0; j < 4; ++j) {
        float4 v = src[j * 4 + q];
        int pl = (j * 4 + q) * 4;
        T[(pl + 0) * 72 + cl] = f2bf(v.x);
        T[(pl + 1) * 72 + cl] = f2bf(v.y);
        T[(pl + 2) * 72 + cl] = f2bf(v.z);
        T[(pl + 3) * 72 + cl] = f2bf(v.w);
    }
    __syncthreads();

    int pl = t >> 2;
    int s  = t & 3;
    short* dst = xT + (long)(px0 + pl) * 256 + c0 + s * 16;
    s16x8 a    = *reinterpret_cast<const s16x8*>(&T[pl * 72 + s * 16]);
    s16x8 bseg = *reinterpret_cast<const s16x8*>(&T[pl * 72 + s * 16 + 8]);
    *reinterpret_cast<s16x8*>(dst)     = a;
    *reinterpret_cast<s16x8*>(dst + 8) = bseg;
}

// ---------------- K1: offset conv via MFMA over xT ----------------
// grid 256 (64-px tiles = one (b,h) row), 256 thr = 4 waves.
// Wave w: px sub-tile [px0 + w*16, +16), oc 0..31 (1 M-frag x 2 N-frags).
// out: off[oc][px] = sum_kk sum_c xT[shift_kk(px)][c] * wOffT[kk][oc][c] + b_off[oc]
__global__ __launch_bounds__(256, 4) void k_offmfma(
        const short* __restrict__ xT, const short* __restrict__ wOffT,
        const float* __restrict__ b_off, float* __restrict__ off) {
    int tid  = threadIdx.x;
    int lane = tid & 63;
    int wv   = tid >> 6;

    int px0  = blockIdx.x * 64 + wv * 16;
    int lm   = lane & 15;
    int lk   = (lane >> 4) * 8;

    int pxA = px0 + lm;                   // A-fragment row
    int h   = (pxA >> 6) & 63;
    int w   = pxA & 63;

    f32x4 acc[2];
    acc[0] = (f32x4)0.f; acc[1] = (f32x4)0.f;

#pragma unroll
    for (int kk = 0; kk < 9; ++kk) {
        const int ki = kk / 3, kj = kk % 3;
        int hh = h + ki - 1, ww = w + kj - 1;
        bool valid = ((unsigned)hh < 64u) & ((unsigned)ww < 64u);
        int srcpx = valid ? (pxA + (ki - 1) * 64 + (kj - 1)) : 0;
        const short* aP = xT + (long)srcpx * 256 + lk;
        const short* bP = wOffT + (long)(kk * 32 + lm) * 256 + lk;
#pragma unroll
        for (int ks = 0; ks < 8; ++ks) {
            s16x8 a = *reinterpret_cast<const s16x8*>(aP + ks * 32);
            if (!valid) a = (s16x8)0;
            s16x8 b0 = *reinterpret_cast<const s16x8*>(bP + ks * 32);
            s16x8 b1 = *reinterpret_cast<const s16x8*>(bP + 16 * 256 + ks * 32);
            acc[0] = __builtin_amdgcn_mfma_f32_16x16x32_bf16(a, b0, acc[0], 0, 0, 0);
            acc[1] = __builtin_amdgcn_mfma_f32_16x16x32_bf16(a, b1, acc[1], 0, 0, 0);
        }
    }

    // D layout: col(lane&15) -> oc, row((lane>>4)*4+j) -> px
#pragma unroll
    for (int nt = 0; nt < 2; ++nt) {
        int oc = nt * 16 + lm;
        if (oc < 27) {
            float bv = b_off[oc];
#pragma unroll
            for (int j = 0; j < 4; ++j) {
                int px = px0 + (lane >> 4) * 4 + j;
                off[oc * NPX_ + px] = acc[nt][j] + bv;
            }
        }
    }
}

// ---------------- K2a: row-blend sample -> val[kk*8+cb][px][32c] bf16 ----------------
__global__ void k_sample(const short* __restrict__ xT, const float* __restrict__ off,
                         short* __restrict__ val) {
    int tid = threadIdx.x;
    int l32 = tid & 31;
    int pxi = tid >> 5;
    int px0 = blockIdx.x * 32;

    int cb = l32 >> 2;
    int cw = (l32 & 3) * 8;

#pragma unroll 1
    for (int kk = 0; kk < 9; ++kk) {
        int ki = kk / 3, kj = kk % 3;
#pragma unroll 1
        for (int it = 0; it < 4; ++it) {
            int p  = px0 + it * 8 + pxi;
            int b  = p >> 12;
            int hw = p & 4095;
            int h  = hw >> 6;
            int wc = hw & 63;

            float dy = off[(2 * kk) * NPX_ + p];
            float dx = off[(2 * kk + 1) * NPX_ + p];
            float mk = off[(18 + kk) * NPX_ + p];
            mk = 1.f / (1.f + __expf(-mk));

            float py  = (float)(h + ki - 1) + dy;
            float pxf = (float)(wc + kj - 1) + dx;
            float y0f = floorf(py), x0f = floorf(pxf);
            float ly = py - y0f, lx = pxf - x0f;
            int y0 = (int)y0f, x0 = (int)x0f;
            int y1 = y0 + 1, x1 = x0 + 1;

            float w00 = (1.f - ly) * (1.f - lx) * mk;
            float w01 = (1.f - ly) * lx * mk;
            float w10 = ly * (1.f - lx) * mk;
            float w11 = ly * lx * mk;
            bool vy0 = (y0 >= 0) & (y0 < H_);
            bool vy1 = (y1 >= 0) & (y1 < H_);
            bool vx0 = (x0 >= 0) & (x0 < W_);
            bool vx1 = (x1 >= 0) & (x1 < W_);
            if (!(vy0 & vx0)) w00 = 0.f;
            if (!(vy0 & vx1)) w01 = 0.f;
            if (!(vy1 & vx0)) w10 = 0.f;
            if (!(vy1 & vx1)) w11 = 0.f;
            int cy0 = min(max(y0, 0), H_ - 1), cy1 = min(max(y1, 0), H_ - 1);
            int cx0 = min(max(x0, 0), W_ - 1), cx1 = min(max(x1, 0), W_ - 1);

            long rb = (long)b * 4096;
            const short* xrow = xT + l32 * 8;
            s16x8 r00 = *reinterpret_cast<const s16x8*>(xrow + (rb + cy0 * 64 + cx0) * 256);
            s16x8 r01 = *reinterpret_cast<const s16x8*>(xrow + (rb + cy0 * 64 + cx1) * 256);
            s16x8 r10 = *reinterpret_cast<const s16x8*>(xrow + (rb + cy1 * 64 + cx0) * 256);
            s16x8 r11 = *reinterpret_cast<const s16x8*>(xrow + (rb + cy1 * 64 + cx1) * 256);

            s16x8 o8;
#pragma unroll
            for (int j = 0; j < 8; ++j) {
                float g = w00 * bf2f(r00[j]) + w01 * bf2f(r01[j])
                        + w10 * bf2f(r10[j]) + w11 * bf2f(r11[j]);
                o8[j] = f2bf(g);
            }
            *reinterpret_cast<s16x8*>(val + ((long)(kk * 8 + cb) * NPX_ + p) * 32 + cw) = o8;
        }
    }
}

// ---------------- K2b: dense MFMA GEMM, 64px x 64oc tiles, prefetch pipeline --------
// grid 1024: bid = ocq*256 + pxt. 256 thr = 4 waves; wave: px half (wv>>1)*32, oc half (wv&1)*32.
__global__ __launch_bounds__(256, 4) void k_gemm(
        const short* __restrict__ val, const short* __restrict__ wT,
        const float* __restrict__ bias, float* __restrict__ out,
        float* __restrict__ gnpart) {
    __shared__ float red[8];

    int tid  = threadIdx.x;
    int lane = tid & 63;
    int wv   = tid >> 6;

    int pxt = blockIdx.x & 255;
    int ocq = blockIdx.x >> 8;

    int px0 = pxt * 64;
    int b   = px0 >> 12;
    int hw0 = px0 & 4095;

    int pxh = (wv >> 1) * 32;
    int oc0 = ocq * 64 + (wv & 1) * 32;

    int lm = lane & 15;
    int lk = (lane >> 4) * 8;

    f32x4 acc[2][2];
#pragma unroll
    for (int i = 0; i < 2; ++i)
#pragma unroll
        for (int j = 0; j < 2; ++j) acc[i][j] = (f32x4)0.f;

    const short* aP = val + (long)(px0 + pxh + lm) * 32 + lk;
    const short* bP = wT + (long)(oc0 + lm) * 256 + lk;

#define LOADA_(d, s) { d[0] = *reinterpret_cast<const s16x8*>(aP + (long)(s) * (NPX_ * 32)); \
                       d[1] = *reinterpret_cast<const s16x8*>(aP + (long)(s) * (NPX_ * 32) + 16 * 32); }
#define LOADB_(d, s) { const short* q = bP + ((s) >> 3) * 65536 + ((s) & 7) * 32; \
                       d[0] = *reinterpret_cast<const s16x8*>(q); \
                       d[1] = *reinterpret_cast<const s16x8*>(q + 16 * 256); }

    s16x8 aC[2], bC[2], aN[2], bN[2];
    LOADA_(aC, 0); LOADB_(bC, 0);
#pragma unroll
    for (int s = 0; s < 72; ++s) {
        if (s < 71) { LOADA_(aN, s + 1); LOADB_(bN, s + 1); }
        acc[0][0] = __builtin_amdgcn_mfma_f32_16x16x32_bf16(aC[0], bC[0], acc[0][0], 0, 0, 0);
        acc[0][1] = __builtin_amdgcn_mfma_f32_16x16x32_bf16(aC[0], bC[1], acc[0][1], 0, 0, 0);
        acc[1][0] = __builtin_amdgcn_mfma_f32_16x16x32_bf16(aC[1], bC[0], acc[1][0], 0, 0, 0);
        acc[1][1] = __builtin_amdgcn_mfma_f32_16x16x32_bf16(aC[1], bC[1], acc[1][1], 0, 0, 0);
        aC[0] = aN[0]; aC[1] = aN[1]; bC[0] = bN[0]; bC[1] = bN[1];
    }
#undef LOADA_
#undef LOADB_

    float s = 0.f, sq = 0.f;
#pragma unroll
    for (int nt = 0; nt < 2; ++nt) {
        int oc = oc0 + nt * 16 + lm;
        float bv = bias[oc];
        float* orow = out + (b * CO_ + oc) * HW_ + hw0 + pxh;
#pragma unroll
        for (int mt = 0; mt < 2; ++mt) {
            f32x4 r = acc[mt][nt];
            r.x += bv; r.y += bv; r.z += bv; r.w += bv;
            s  += r.x + r.y + r.z + r.w;
            sq += r.x * r.x + r.y * r.y + r.z * r.z + r.w * r.w;
            *reinterpret_cast<f32x4*>(orow + mt * 16 + (lane >> 4) * 4) = r;
        }
    }
#pragma unroll
    for (int o = 32; o > 0; o >>= 1) {
        s  += __shfl_down(s, o, 64);
        sq += __shfl_down(sq, o, 64);
    }
    if (lane == 0) { red[wv * 2] = s; red[wv * 2 + 1] = sq; }
    __syncthreads();
    if (tid == 0) {
        float S = 0.f, SQ = 0.f;
#pragma unroll
        for (int k = 0; k < 4; ++k) { S += red[k * 2]; SQ += red[k * 2 + 1]; }
        gnpart[blockIdx.x * 2]     = S;
        gnpart[blockIdx.x * 2 + 1] = SQ;
    }
}

// ---------------- K4: finalize stats. grid 4 (batch), 256 thr ----------------
// gemm bid = ocq*256 + (b*64 + i); thread t covers ocq=t>>6, i=t&63
__global__ void k_gn_stats(const float* __restrict__ part, float* __restrict__ stats) {
    __shared__ float red[8];
    int b = blockIdx.x, t = threadIdx.x;
    int idx = (t >> 6) * 256 + b * 64 + (t & 63);
    float2 v = reinterpret_cast<const float2*>(part)[idx];
    float s = v.x, sq = v.y;
#pragma unroll
    for (int o = 32; o > 0; o >>= 1) {
        s  += __shfl_down(s, o, 64);
        sq += __shfl_down(sq, o, 64);
    }
    int wv = t >> 6;
    if ((t & 63) == 0) { red[wv * 2] = s; red[wv * 2 + 1] = sq; }
    __syncthreads();
    if (t == 0) {
        float S = 0.f, SQ = 0.f;
#pragma unroll
        for (int k = 0; k < 4; ++k) { S += red[k * 2]; SQ += red[k * 2 + 1]; }
        const float n = (float)(CO_ * HW_);
        float mean = S / n;
        float var  = SQ / n - mean * mean;
        stats[b * 2] = mean;
        stats[b * 2 + 1] = rsqrtf(var + GN_EPS_);
    }
}

// ---------------- K5: normalize + affine + relu ----------------
__global__ void k_gn_apply(float* __restrict__ y, const float* __restrict__ stats,
                           const float* __restrict__ gamma, const float* __restrict__ beta) {
    int e4 = blockIdx.x * 256 + threadIdx.x;
    int b  = e4 >> 18;
    int oc = (e4 >> 10) & 255;
    float mean = stats[b * 2], rstd = stats[b * 2 + 1];
    float g  = gamma[oc] * rstd;
    float bb = beta[oc] - mean * g;
    float4* p = reinterpret_cast<float4*>(y);
    float4 v = p[e4];
    v.x = fmaxf(v.x * g + bb, 0.f);
    v.y = fmaxf(v.y * g + bb, 0.f);
    v.z = fmaxf(v.z * g + bb, 0.f);
    v.w = fmaxf(v.w * g + bb, 0.f);
    p[e4] = v;
}

extern "C" void kernel_launch(void* const* d_in, const int* in_sizes, int n_in,
                              void* d_out, int out_size, void* d_ws, size_t ws_size,
                              hipStream_t stream) {
    const float* x     = (const float*)d_in[0];
    const float* w_off = (const float*)d_in[1];
    const float* b_off = (const float*)d_in[2];
    const float* w     = (const float*)d_in[3];
    const float* bias  = (const float*)d_in[4];
    const float* gamma = (const float*)d_in[5];
    const float* beta  = (const float*)d_in[6];
    float* out = (float*)d_out;

    // ws: [off 1.77MB][wT 1.18MB][wOffT 0.15MB][gnpart 8KB][stats][xT 8.4MB][val 75.5MB]
    float* Wp     = (float*)d_ws;
    float* off    = Wp;                                 // 442368 floats
    short* wT     = (short*)(off + 27 * NPX_);          // 589824 shorts
    short* wOffT  = wT + 9 * 256 * 256;                 // 73728 shorts
    float* gnpart = (float*)(wOffT + 9 * 32 * 256);     // 2048 floats
    float* stats  = gnpart + 2048;                      // 8 floats
    short* xT     = (short*)(stats + 8);                // 4194304 shorts
    short* val    = xT + (long)NPX_ * 256;              // 37748736 shorts

    k_prep_w<<<256, 256, 0, stream>>>(w, wT);
    k_prep_woff<<<32, 256, 0, stream>>>(w_off, wOffT);
    k_xpose<<<1024, 256, 0, stream>>>(x, xT);
    k_offmfma<<<256, 256, 0, stream>>>(xT, wOffT, b_off, off);
    k_sample<<<512, 256, 0, stream>>>(xT, off, val);
    k_gemm<<<1024, 256, 0, stream>>>(val, wT, bias, out, gnpart);
    k_gn_stats<<<4, 256, 0, stream>>>(gnpart, stats);
    k_gn_apply<<<4096, 256, 0, stream>>>(out, stats, gamma, beta);
}

// Round 7
// 196.923 us; speedup vs baseline: 1.8012x; 1.2933x over previous
//
#include <hip/hip_runtime.h>

#define B_ 4
#define C_ 256
#define H_ 64
#define W_ 64
#define HW_ 4096
#define CO_ 256
#define NPX_ 16384
#define GN_EPS_ 1e-5f

typedef float f32x4 __attribute__((ext_vector_type(4)));
typedef short s16x8 __attribute__((ext_vector_type(8)));

__device__ __forceinline__ short f2bf(float f) {
    union { float f; unsigned u; } v; v.f = f;
    unsigned r = (v.u + 0x7FFFu + ((v.u >> 16) & 1u)) >> 16;
    return (short)(r & 0xFFFFu);
}
__device__ __forceinline__ float bf2f(short s) {
    union { unsigned u; float f; } v; v.u = ((unsigned)s & 0xFFFFu) << 16;
    return v.f;
}

__device__ __forceinline__ void gld_lds16(const void* g, void* l) {
    __builtin_amdgcn_global_load_lds(
        (const __attribute__((address_space(1))) unsigned*)g,
        (__attribute__((address_space(3))) unsigned*)l,
        16, 0, 0);
}

// ---------------- K0: w[oc][c][kk] -> wT[kk][oc][c] bf16 ----------------
__global__ void k_prep_w(const float* __restrict__ w, short* __restrict__ wT) {
    int oc = blockIdx.x, c = threadIdx.x;
    const float* src = w + (oc * 256 + c) * 9;
    float v[9];
#pragma unroll
    for (int t = 0; t < 9; ++t) v[t] = src[t];
#pragma unroll
    for (int t = 0; t < 9; ++t) wT[(t * 256 + oc) * 256 + c] = f2bf(v[t]);
}

// ---------------- K0a: w_off -> wOffT[kk][32][256] bf16 (rows 27..31 zero) ----
__global__ void k_prep_woff(const float* __restrict__ w_off, short* __restrict__ wOffT) {
    int o = blockIdx.x;
    int c = threadIdx.x;
    if (o < 27) {
        const float* src = w_off + (o * 256 + c) * 9;
#pragma unroll
        for (int t = 0; t < 9; ++t)
            wOffT[(t * 32 + o) * 256 + c] = f2bf(src[t]);
    } else {
#pragma unroll
        for (int t = 0; t < 9; ++t)
            wOffT[(t * 32 + o) * 256 + c] = 0;
    }
}

// ---------------- K0b: x[b][c][hw] f32 -> xT[b][hw][c] bf16 ----------------
__global__ void k_xpose(const float* __restrict__ x, short* __restrict__ xT) {
    __shared__ short T[64 * 72];

    int bx  = blockIdx.x;
    int px0 = (bx & 255) * 64;
    int c0  = (bx >> 8) * 64;
    int b   = px0 >> 12;
    int hw0 = px0 & 4095;

    int t  = threadIdx.x;
    int cl = t & 63;
    int q  = t >> 6;

    const float4* src = reinterpret_cast<const float4*>(
        x + (long)(b * 256 + c0 + cl) * 4096 + hw0);
#pragma unroll
    for (int j = 0; j < 4; ++j) {
        float4 v = src[j * 4 + q];
        int pl = (j * 4 + q) * 4;
        T[(pl + 0) * 72 + cl] = f2bf(v.x);
        T[(pl + 1) * 72 + cl] = f2bf(v.y);
        T[(pl + 2) * 72 + cl] = f2bf(v.z);
        T[(pl + 3) * 72 + cl] = f2bf(v.w);
    }
    __syncthreads();

    int pl = t >> 2;
    int s  = t & 3;
    short* dst = xT + (long)(px0 + pl) * 256 + c0 + s * 16;
    s16x8 a    = *reinterpret_cast<const s16x8*>(&T[pl * 72 + s * 16]);
    s16x8 bseg = *reinterpret_cast<const s16x8*>(&T[pl * 72 + s * 16 + 8]);
    *reinterpret_cast<s16x8*>(dst)     = a;
    *reinterpret_cast<s16x8*>(dst + 8) = bseg;
}

// ---------------- K1: offset conv via MFMA over xT ----------------
__global__ __launch_bounds__(256, 4) void k_offmfma(
        const short* __restrict__ xT, const short* __restrict__ wOffT,
        const float* __restrict__ b_off, float* __restrict__ off) {
    int tid  = threadIdx.x;
    int lane = tid & 63;
    int wv   = tid >> 6;

    int px0  = blockIdx.x * 64 + wv * 16;
    int lm   = lane & 15;
    int lk   = (lane >> 4) * 8;

    int pxA = px0 + lm;
    int h   = (pxA >> 6) & 63;
    int w   = pxA & 63;

    f32x4 acc[2];
    acc[0] = (f32x4)0.f; acc[1] = (f32x4)0.f;

#pragma unroll
    for (int kk = 0; kk < 9; ++kk) {
        const int ki = kk / 3, kj = kk % 3;
        int hh = h + ki - 1, ww = w + kj - 1;
        bool valid = ((unsigned)hh < 64u) & ((unsigned)ww < 64u);
        int srcpx = valid ? (pxA + (ki - 1) * 64 + (kj - 1)) : 0;
        const short* aP = xT + (long)srcpx * 256 + lk;
        const short* bP = wOffT + (long)(kk * 32 + lm) * 256 + lk;
#pragma unroll
        for (int ks = 0; ks < 8; ++ks) {
            s16x8 a = *reinterpret_cast<const s16x8*>(aP + ks * 32);
            if (!valid) a = (s16x8)0;
            s16x8 b0 = *reinterpret_cast<const s16x8*>(bP + ks * 32);
            s16x8 b1 = *reinterpret_cast<const s16x8*>(bP + 16 * 256 + ks * 32);
            acc[0] = __builtin_amdgcn_mfma_f32_16x16x32_bf16(a, b0, acc[0], 0, 0, 0);
            acc[1] = __builtin_amdgcn_mfma_f32_16x16x32_bf16(a, b1, acc[1], 0, 0, 0);
        }
    }

#pragma unroll
    for (int nt = 0; nt < 2; ++nt) {
        int oc = nt * 16 + lm;
        if (oc < 27) {
            float bv = b_off[oc];
#pragma unroll
            for (int j = 0; j < 4; ++j) {
                int px = px0 + (lane >> 4) * 4 + j;
                off[oc * NPX_ + px] = acc[nt][j] + bv;
            }
        }
    }
}

// ---------------- K2a: row-blend sample -> val[kk*8+cb][px][32c] bf16 ----------------
__global__ void k_sample(const short* __restrict__ xT, const float* __restrict__ off,
                         short* __restrict__ val) {
    int tid = threadIdx.x;
    int l32 = tid & 31;
    int pxi = tid >> 5;
    int px0 = blockIdx.x * 32;

    int cb = l32 >> 2;
    int cw = (l32 & 3) * 8;

#pragma unroll 1
    for (int kk = 0; kk < 9; ++kk) {
        int ki = kk / 3, kj = kk % 3;
#pragma unroll 1
        for (int it = 0; it < 4; ++it) {
            int p  = px0 + it * 8 + pxi;
            int b  = p >> 12;
            int hw = p & 4095;
            int h  = hw >> 6;
            int wc = hw & 63;

            float dy = off[(2 * kk) * NPX_ + p];
            float dx = off[(2 * kk + 1) * NPX_ + p];
            float mk = off[(18 + kk) * NPX_ + p];
            mk = 1.f / (1.f + __expf(-mk));

            float py  = (float)(h + ki - 1) + dy;
            float pxf = (float)(wc + kj - 1) + dx;
            float y0f = floorf(py), x0f = floorf(pxf);
            float ly = py - y0f, lx = pxf - x0f;
            int y0 = (int)y0f, x0 = (int)x0f;
            int y1 = y0 + 1, x1 = x0 + 1;

            float w00 = (1.f - ly) * (1.f - lx) * mk;
            float w01 = (1.f - ly) * lx * mk;
            float w10 = ly * (1.f - lx) * mk;
            float w11 = ly * lx * mk;
            bool vy0 = (y0 >= 0) & (y0 < H_);
            bool vy1 = (y1 >= 0) & (y1 < H_);
            bool vx0 = (x0 >= 0) & (x0 < W_);
            bool vx1 = (x1 >= 0) & (x1 < W_);
            if (!(vy0 & vx0)) w00 = 0.f;
            if (!(vy0 & vx1)) w01 = 0.f;
            if (!(vy1 & vx0)) w10 = 0.f;
            if (!(vy1 & vx1)) w11 = 0.f;
            int cy0 = min(max(y0, 0), H_ - 1), cy1 = min(max(y1, 0), H_ - 1);
            int cx0 = min(max(x0, 0), W_ - 1), cx1 = min(max(x1, 0), W_ - 1);

            long rb = (long)b * 4096;
            const short* xrow = xT + l32 * 8;
            s16x8 r00 = *reinterpret_cast<const s16x8*>(xrow + (rb + cy0 * 64 + cx0) * 256);
            s16x8 r01 = *reinterpret_cast<const s16x8*>(xrow + (rb + cy0 * 64 + cx1) * 256);
            s16x8 r10 = *reinterpret_cast<const s16x8*>(xrow + (rb + cy1 * 64 + cx0) * 256);
            s16x8 r11 = *reinterpret_cast<const s16x8*>(xrow + (rb + cy1 * 64 + cx1) * 256);

            s16x8 o8;
#pragma unroll
            for (int j = 0; j < 8; ++j) {
                float g = w00 * bf2f(r00[j]) + w01 * bf2f(r01[j])
                        + w10 * bf2f(r10[j]) + w11 * bf2f(r11[j]);
                o8[j] = f2bf(g);
            }
            *reinterpret_cast<s16x8*>(val + ((long)(kk * 8 + cb) * NPX_ + p) * 32 + cw) = o8;
        }
    }
}

// ---------------- K2b: LDS-staged double-buffered MFMA GEMM ----------------
// grid 256: bid = ocq*128 + pxt. Tile 128px x 128oc, BK=64, 512 thr = 8 waves.
// Wave wv: px-half (wv&1)*64, oc-quarter (wv>>1)*32. acc 4x2 frags.
// A staged via global_load_lds from val (quad-XOR swizzled source), B from wT.
__global__ __launch_bounds__(512, 1) void k_gemm(
        const short* __restrict__ val, const short* __restrict__ wT,
        const float* __restrict__ bias, float* __restrict__ out,
        float* __restrict__ gnpart) {
    __shared__ char lds[65536];          // [buf][A 16K][B 16K]
    __shared__ float red[16];

    int tid  = threadIdx.x;
    int lane = tid & 63;
    int wv   = tid >> 6;

    int pxt = blockIdx.x & 127;
    int ocq = blockIdx.x >> 7;

    int px0 = pxt * 128;
    int b   = px0 >> 12;
    int hw0 = px0 & 4095;

    int wm = wv & 1;                      // px half
    int wn = wv >> 1;                     // oc quarter

    int lm = lane & 15;
    int kq = lane >> 4;                   // c-quad of the MFMA fragment

    // staging constants (per lane)
    int rsub = lane >> 2;                 // row-within-16 for glds
    int qg   = (lane & 3) ^ ((lane >> 3) & 3);   // pre-swizzled source quad
    // read-side swizzled quad byte offset
    int qoff = ((kq ^ ((lane >> 1) & 3)) << 4);

    const char* valb = (const char*)val;
    const char* wTb  = (const char*)wT;

    f32x4 acc[4][2];
#pragma unroll
    for (int i = 0; i < 4; ++i)
#pragma unroll
        for (int j = 0; j < 2; ++j) acc[i][j] = (f32x4)0.f;

    // ---- STAGE(k, buf): 2 A-glds + 2 B-glds per wave ----
#define STAGE_(kidx, bufbase)                                                        \
    {                                                                                \
        int kk_ = (kidx) >> 2, cpair_ = (kidx) & 3;                                  \
        _Pragma("unroll")                                                            \
        for (int g = 0; g < 2; ++g) {                                                \
            int i_   = wv * 2 + g;                                                   \
            int R_   = i_ * 16 + rsub;            /* 0..255 */                       \
            int ksub_ = R_ >> 7;                                                     \
            int rl_   = R_ & 127;                                                    \
            /* A: row rl_ = px_local */                                              \
            const char* srcA = valb + ((long)((2 * (kidx) + ksub_) * NPX_            \
                               + px0 + rl_)) * 64 + qg * 16;                         \
            gld_lds16(srcA, (void*)(lds + (bufbase) + i_ * 1024));                   \
            /* B: row rl_ = oc_local */                                              \
            const char* srcB = wTb + ((long)(kk_ * 256 + ocq * 128 + rl_)) * 512     \
                               + cpair_ * 128 + ksub_ * 64 + qg * 16;                \
            gld_lds16(srcB, (void*)(lds + (bufbase) + 16384 + i_ * 1024));           \
        }                                                                            \
    }

    // ---- COMPUTE(buf) ----
#define COMPUTE_(bufbase)                                                            \
    {                                                                                \
        _Pragma("unroll")                                                            \
        for (int ksub = 0; ksub < 2; ++ksub) {                                       \
            const char* Ab = lds + (bufbase) + ksub * 8192;                          \
            const char* Bb = lds + (bufbase) + 16384 + ksub * 8192;                  \
            s16x8 a[4], bf[2];                                                       \
            _Pragma("unroll")                                                        \
            for (int mf = 0; mf < 4; ++mf)                                           \
                a[mf] = *reinterpret_cast<const s16x8*>(                             \
                    Ab + (wm * 64 + mf * 16 + lm) * 64 + qoff);                      \
            _Pragma("unroll")                                                        \
            for (int nf = 0; nf < 2; ++nf)                                           \
                bf[nf] = *reinterpret_cast<const s16x8*>(                            \
                    Bb + (wn * 32 + nf * 16 + lm) * 64 + qoff);                      \
            _Pragma("unroll")                                                        \
            for (int mf = 0; mf < 4; ++mf)                                           \
                _Pragma("unroll")                                                    \
                for (int nf = 0; nf < 2; ++nf)                                       \
                    acc[mf][nf] = __builtin_amdgcn_mfma_f32_16x16x32_bf16(           \
                        a[mf], bf[nf], acc[mf][nf], 0, 0, 0);                        \
        }                                                                            \
    }

    STAGE_(0, 0);
    __syncthreads();

    int cur = 0;
#pragma unroll 1
    for (int k = 0; k < 36; ++k) {
        if (k < 35) STAGE_(k + 1, (cur ^ 1) * 32768);
        COMPUTE_(cur * 32768);
        __syncthreads();                  // drains vmcnt (stage k+1 complete)
        cur ^= 1;
    }
#undef STAGE_
#undef COMPUTE_

    // ---- epilogue: bias + store + GN partial ----
    float s = 0.f, sq = 0.f;
#pragma unroll
    for (int nf = 0; nf < 2; ++nf) {
        int oc = ocq * 128 + wn * 32 + nf * 16 + lm;
        float bv = bias[oc];
        float* orow = out + (b * CO_ + oc) * HW_ + hw0 + wm * 64;
#pragma unroll
        for (int mf = 0; mf < 4; ++mf) {
            f32x4 r = acc[mf][nf];
            r.x += bv; r.y += bv; r.z += bv; r.w += bv;
            s  += r.x + r.y + r.z + r.w;
            sq += r.x * r.x + r.y * r.y + r.z * r.z + r.w * r.w;
            *reinterpret_cast<f32x4*>(orow + mf * 16 + kq * 4) = r;
        }
    }
#pragma unroll
    for (int o = 32; o > 0; o >>= 1) {
        s  += __shfl_down(s, o, 64);
        sq += __shfl_down(sq, o, 64);
    }
    if (lane == 0) { red[wv * 2] = s; red[wv * 2 + 1] = sq; }
    __syncthreads();
    if (tid == 0) {
        float S = 0.f, SQ = 0.f;
#pragma unroll
        for (int k = 0; k < 8; ++k) { S += red[k * 2]; SQ += red[k * 2 + 1]; }
        gnpart[blockIdx.x * 2]     = S;
        gnpart[blockIdx.x * 2 + 1] = SQ;
    }
}

// ---------------- K4: finalize stats. grid 4 (batch), 64 thr ----------------
// gemm bid = ocq*128 + pxt, pxt = b*32 + i
__global__ void k_gn_stats(const float* __restrict__ part, float* __restrict__ stats) {
    int b = blockIdx.x, t = threadIdx.x;
    int idx = (t >> 5) * 128 + b * 32 + (t & 31);
    float2 v = reinterpret_cast<const float2*>(part)[idx];
    float s = v.x, sq = v.y;
#pragma unroll
    for (int o = 32; o > 0; o >>= 1) {
        s  += __shfl_down(s, o, 64);
        sq += __shfl_down(sq, o, 64);
    }
    if (t == 0) {
        const float n = (float)(CO_ * HW_);
        float mean = s / n;
        float var  = sq / n - mean * mean;
        stats[b * 2] = mean;
        stats[b * 2 + 1] = rsqrtf(var + GN_EPS_);
    }
}

// ---------------- K5: normalize + affine + relu ----------------
__global__ void k_gn_apply(float* __restrict__ y, const float* __restrict__ stats,
                           const float* __restrict__ gamma, const float* __restrict__ beta) {
    int e4 = blockIdx.x * 256 + threadIdx.x;
    int b  = e4 >> 18;
    int oc = (e4 >> 10) & 255;
    float mean = stats[b * 2], rstd = stats[b * 2 + 1];
    float g  = gamma[oc] * rstd;
    float bb = beta[oc] - mean * g;
    float4* p = reinterpret_cast<float4*>(y);
    float4 v = p[e4];
    v.x = fmaxf(v.x * g + bb, 0.f);
    v.y = fmaxf(v.y * g + bb, 0.f);
    v.z = fmaxf(v.z * g + bb, 0.f);
    v.w = fmaxf(v.w * g + bb, 0.f);
    p[e4] = v;
}

extern "C" void kernel_launch(void* const* d_in, const int* in_sizes, int n_in,
                              void* d_out, int out_size, void* d_ws, size_t ws_size,
                              hipStream_t stream) {
    const float* x     = (const float*)d_in[0];
    const float* w_off = (const float*)d_in[1];
    const float* b_off = (const float*)d_in[2];
    const float* w     = (const float*)d_in[3];
    const float* bias  = (const float*)d_in[4];
    const float* gamma = (const float*)d_in[5];
    const float* beta  = (const float*)d_in[6];
    float* out = (float*)d_out;

    float* Wp     = (float*)d_ws;
    float* off    = Wp;                                 // 442368 floats
    short* wT     = (short*)(off + 27 * NPX_);          // 589824 shorts
    short* wOffT  = wT + 9 * 256 * 256;                 // 73728 shorts
    float* gnpart = (float*)(wOffT + 9 * 32 * 256);     // 2048 floats
    float* stats  = gnpart + 2048;                      // 8 floats
    short* xT     = (short*)(stats + 8);                // 4194304 shorts
    short* val    = xT + (long)NPX_ * 256;              // 37748736 shorts

    k_prep_w<<<256, 256, 0, stream>>>(w, wT);
    k_prep_woff<<<32, 256, 0, stream>>>(w_off, wOffT);
    k_xpose<<<1024, 256, 0, stream>>>(x, xT);
    k_offmfma<<<256, 256, 0, stream>>>(xT, wOffT, b_off, off);
    k_sample<<<512, 256, 0, stream>>>(xT, off, val);
    k_gemm<<<256, 512, 0, stream>>>(val, wT, bias, out, gnpart);
    k_gn_stats<<<4, 64, 0, stream>>>(gnpart, stats);
    k_gn_apply<<<4096, 256, 0, stream>>>(out, stats, gamma, beta);
}

// Round 8
// 178.876 us; speedup vs baseline: 1.9829x; 1.1009x over previous
//
#include <hip/hip_runtime.h>

#define B_ 4
#define C_ 256
#define H_ 64
#define W_ 64
#define HW_ 4096
#define CO_ 256
#define NPX_ 16384
#define GN_EPS_ 1e-5f

typedef float f32x4 __attribute__((ext_vector_type(4)));
typedef short s16x8 __attribute__((ext_vector_type(8)));

__device__ __forceinline__ short f2bf(float f) {
    union { float f; unsigned u; } v; v.f = f;
    unsigned r = (v.u + 0x7FFFu + ((v.u >> 16) & 1u)) >> 16;
    return (short)(r & 0xFFFFu);
}
__device__ __forceinline__ float bf2f(short s) {
    union { unsigned u; float f; } v; v.u = ((unsigned)s & 0xFFFFu) << 16;
    return v.f;
}

__device__ __forceinline__ void gld_lds16(const void* g, void* l) {
    __builtin_amdgcn_global_load_lds(
        (const __attribute__((address_space(1))) unsigned*)g,
        (__attribute__((address_space(3))) unsigned*)l,
        16, 0, 0);
}

// ---------------- K0: w[oc][c][kk] -> wT[kk][oc][c] bf16 ----------------
__global__ void k_prep_w(const float* __restrict__ w, short* __restrict__ wT) {
    int oc = blockIdx.x, c = threadIdx.x;
    const float* src = w + (oc * 256 + c) * 9;
    float v[9];
#pragma unroll
    for (int t = 0; t < 9; ++t) v[t] = src[t];
#pragma unroll
    for (int t = 0; t < 9; ++t) wT[(t * 256 + oc) * 256 + c] = f2bf(v[t]);
}

// ---------------- K0a: w_off -> wOffT[kk][32][256] bf16 (rows 27..31 zero) ----
__global__ void k_prep_woff(const float* __restrict__ w_off, short* __restrict__ wOffT) {
    int o = blockIdx.x;
    int c = threadIdx.x;
    if (o < 27) {
        const float* src = w_off + (o * 256 + c) * 9;
#pragma unroll
        for (int t = 0; t < 9; ++t)
            wOffT[(t * 32 + o) * 256 + c] = f2bf(src[t]);
    } else {
#pragma unroll
        for (int t = 0; t < 9; ++t)
            wOffT[(t * 32 + o) * 256 + c] = 0;
    }
}

// ---------------- K0b: x[b][c][hw] f32 -> xT[b][hw][c] bf16 ----------------
__global__ void k_xpose(const float* __restrict__ x, short* __restrict__ xT) {
    __shared__ short T[64 * 72];

    int bx  = blockIdx.x;
    int px0 = (bx & 255) * 64;
    int c0  = (bx >> 8) * 64;
    int b   = px0 >> 12;
    int hw0 = px0 & 4095;

    int t  = threadIdx.x;
    int cl = t & 63;
    int q  = t >> 6;

    const float4* src = reinterpret_cast<const float4*>(
        x + (long)(b * 256 + c0 + cl) * 4096 + hw0);
#pragma unroll
    for (int j = 0; j < 4; ++j) {
        float4 v = src[j * 4 + q];
        int pl = (j * 4 + q) * 4;
        T[(pl + 0) * 72 + cl] = f2bf(v.x);
        T[(pl + 1) * 72 + cl] = f2bf(v.y);
        T[(pl + 2) * 72 + cl] = f2bf(v.z);
        T[(pl + 3) * 72 + cl] = f2bf(v.w);
    }
    __syncthreads();

    int pl = t >> 2;
    int s  = t & 3;
    short* dst = xT + (long)(px0 + pl) * 256 + c0 + s * 16;
    s16x8 a    = *reinterpret_cast<const s16x8*>(&T[pl * 72 + s * 16]);
    s16x8 bseg = *reinterpret_cast<const s16x8*>(&T[pl * 72 + s * 16 + 8]);
    *reinterpret_cast<s16x8*>(dst)     = a;
    *reinterpret_cast<s16x8*>(dst + 8) = bseg;
}

// ---------------- K1: offset conv via MFMA, K-split x4 ----------------
// grid (256, 4): bx = 64-px tile, by = 64-c chunk. 256 thr = 4 waves.
// partial: offp[by][27][NPX]
__global__ __launch_bounds__(256, 4) void k_offmfma(
        const short* __restrict__ xT, const short* __restrict__ wOffT,
        float* __restrict__ offp) {
    int tid  = threadIdx.x;
    int lane = tid & 63;
    int wv   = tid >> 6;

    int px0  = blockIdx.x * 64 + wv * 16;
    int cc0  = blockIdx.y * 64;
    int lm   = lane & 15;
    int lk   = cc0 + (lane >> 4) * 8;

    int pxA = px0 + lm;
    int h   = (pxA >> 6) & 63;
    int w   = pxA & 63;

    f32x4 acc[2];
    acc[0] = (f32x4)0.f; acc[1] = (f32x4)0.f;

#pragma unroll
    for (int kk = 0; kk < 9; ++kk) {
        const int ki = kk / 3, kj = kk % 3;
        int hh = h + ki - 1, ww = w + kj - 1;
        bool valid = ((unsigned)hh < 64u) & ((unsigned)ww < 64u);
        int srcpx = valid ? (pxA + (ki - 1) * 64 + (kj - 1)) : 0;
        const short* aP = xT + (long)srcpx * 256 + lk;
        const short* bP = wOffT + (long)(kk * 32 + lm) * 256 + lk;
#pragma unroll
        for (int ks = 0; ks < 2; ++ks) {
            s16x8 a = *reinterpret_cast<const s16x8*>(aP + ks * 32);
            if (!valid) a = (s16x8)0;
            s16x8 b0 = *reinterpret_cast<const s16x8*>(bP + ks * 32);
            s16x8 b1 = *reinterpret_cast<const s16x8*>(bP + 16 * 256 + ks * 32);
            acc[0] = __builtin_amdgcn_mfma_f32_16x16x32_bf16(a, b0, acc[0], 0, 0, 0);
            acc[1] = __builtin_amdgcn_mfma_f32_16x16x32_bf16(a, b1, acc[1], 0, 0, 0);
        }
    }

    float* op = offp + (long)blockIdx.y * 27 * NPX_;
#pragma unroll
    for (int nt = 0; nt < 2; ++nt) {
        int oc = nt * 16 + lm;
        if (oc < 27) {
#pragma unroll
            for (int j = 0; j < 4; ++j) {
                int px = px0 + (lane >> 4) * 4 + j;
                op[oc * NPX_ + px] = acc[nt][j];
            }
        }
    }
}

// ---------------- K1b: reduce K-split partials + bias ----------------
__global__ void k_offreduce(const float* __restrict__ offp, const float* __restrict__ b_off,
                            float* __restrict__ off) {
    int idx = blockIdx.x * 256 + threadIdx.x;      // 442368
    int oc  = idx >> 14;
    float s = b_off[oc];
#pragma unroll
    for (int j = 0; j < 4; ++j) s += offp[(long)j * 27 * NPX_ + idx];
    off[idx] = s;
}

// ---------------- K2: FUSED sample + MFMA GEMM + GN partial ----------------
// grid 256: bid = pxt (64-px tile = one (b,h) row). 512 thr = 8 waves.
// Tile: 64 px x 256 oc, BK=64, 36 K-tiles (kk outer, c-quarter inner).
// A: sampled on the fly (row-blend from xT) -> ds_write swizzled. 8 KB/buf.
// B: wT staged via global_load_lds, source pre-swizzled. 32 KB/buf.
// Wave wv: px-half wm=(wv&1)*32, oc-quarter wn=(wv>>1)*64. acc 2x4.
__global__ __launch_bounds__(512, 1) void k_fused(
        const short* __restrict__ xT, const float* __restrict__ off,
        const short* __restrict__ wT, const float* __restrict__ bias,
        float* __restrict__ out, float* __restrict__ gnpart) {
    __shared__ __attribute__((aligned(16))) char lds[81920];  // 2 x (A 8K @0, B 32K @8K)
    __shared__ float red[16];

    int tid  = threadIdx.x;
    int lane = tid & 63;
    int wv   = tid >> 6;

    int px0 = blockIdx.x * 64;
    int b   = px0 >> 12;
    int hw0 = px0 & 4095;
    int h   = hw0 >> 6;
    long rb = (long)b * 4096;

    // sampling role
    int spx = tid >> 3;                  // 0..63 (= w coordinate)
    int j8  = (tid & 7) * 8;             // channel octet base within 64-c tile
    int pg  = px0 + spx;                 // global pixel
    int abyte = spx * 128 + (((tid & 7) << 4) ^ ((spx & 7) << 4));

    // B staging constants
    int brow_lane = lane >> 3;           // row within 8-row group
    int bqg = (((lane & 7) ^ brow_lane) & 7) << 4;

    // mfma role
    int wm = (wv & 1) * 32;
    int wn = (wv >> 1) * 64;
    int lm = lane & 15;
    int kq = lane >> 4;

    const char* wTb = (const char*)wT;

    f32x4 acc[2][4];
#pragma unroll
    for (int i = 0; i < 2; ++i)
#pragma unroll
        for (int j = 0; j < 4; ++j) acc[i][j] = (f32x4)0.f;

    // persistent per-px sampling state (recomputed when kk changes)
    float sw00 = 0.f, sw01 = 0.f, sw10 = 0.f, sw11 = 0.f;
    const short *p00 = xT, *p01 = xT, *p10 = xT, *p11 = xT;

#define STAGE_(t, buf)                                                               \
    {                                                                                \
        int kk_ = (t) >> 2, cq_ = (t) & 3;                                           \
        if (((t) & 3) == 0) {                                                        \
            int ki_ = kk_ / 3, kj_ = kk_ % 3;                                        \
            float dy = off[(2 * kk_) * NPX_ + pg];                                   \
            float dx = off[(2 * kk_ + 1) * NPX_ + pg];                               \
            float mk = off[(18 + kk_) * NPX_ + pg];                                  \
            mk = 1.f / (1.f + __expf(-mk));                                          \
            float py  = (float)(h + ki_ - 1) + dy;                                   \
            float pxf = (float)(spx + kj_ - 1) + dx;                                 \
            float y0f = floorf(py), x0f = floorf(pxf);                               \
            float ly = py - y0f, lx = pxf - x0f;                                     \
            int y0 = (int)y0f, x0 = (int)x0f;                                        \
            int y1 = y0 + 1, x1 = x0 + 1;                                            \
            sw00 = (1.f - ly) * (1.f - lx) * mk;                                     \
            sw01 = (1.f - ly) * lx * mk;                                             \
            sw10 = ly * (1.f - lx) * mk;                                             \
            sw11 = ly * lx * mk;                                                     \
            bool vy0 = (y0 >= 0) & (y0 < H_);                                        \
            bool vy1 = (y1 >= 0) & (y1 < H_);                                        \
            bool vx0 = (x0 >= 0) & (x0 < W_);                                        \
            bool vx1 = (x1 >= 0) & (x1 < W_);                                        \
            if (!(vy0 & vx0)) sw00 = 0.f;                                            \
            if (!(vy0 & vx1)) sw01 = 0.f;                                            \
            if (!(vy1 & vx0)) sw10 = 0.f;                                            \
            if (!(vy1 & vx1)) sw11 = 0.f;                                            \
            int cy0 = min(max(y0, 0), H_ - 1), cy1 = min(max(y1, 0), H_ - 1);        \
            int cx0 = min(max(x0, 0), W_ - 1), cx1 = min(max(x1, 0), W_ - 1);        \
            p00 = xT + (rb + cy0 * 64 + cx0) * 256;                                  \
            p01 = xT + (rb + cy0 * 64 + cx1) * 256;                                  \
            p10 = xT + (rb + cy1 * 64 + cx0) * 256;                                  \
            p11 = xT + (rb + cy1 * 64 + cx1) * 256;                                  \
        }                                                                            \
        _Pragma("unroll")                                                            \
        for (int g = 0; g < 4; ++g) {                                                \
            int row8 = wv * 4 + g;               /* 8-oc-row group 0..31 */          \
            int ocr  = row8 * 8 + brow_lane;                                         \
            const char* srcB = wTb + ((long)(kk_ * 256 + ocr) << 9)                  \
                               + cq_ * 128 + bqg;                                    \
            gld_lds16(srcB, (void*)(lds + (buf) * 40960 + 8192 + row8 * 1024));      \
        }                                                                            \
        int coff = cq_ * 64 + j8;                                                    \
        s16x8 r00 = *reinterpret_cast<const s16x8*>(p00 + coff);                     \
        s16x8 r01 = *reinterpret_cast<const s16x8*>(p01 + coff);                     \
        s16x8 r10 = *reinterpret_cast<const s16x8*>(p10 + coff);                     \
        s16x8 r11 = *reinterpret_cast<const s16x8*>(p11 + coff);                     \
        s16x8 o8;                                                                    \
        _Pragma("unroll")                                                            \
        for (int jj = 0; jj < 8; ++jj) {                                             \
            float g2 = sw00 * bf2f(r00[jj]) + sw01 * bf2f(r01[jj])                   \
                     + sw10 * bf2f(r10[jj]) + sw11 * bf2f(r11[jj]);                  \
            o8[jj] = f2bf(g2);                                                       \
        }                                                                            \
        *reinterpret_cast<s16x8*>(lds + (buf) * 40960 + abyte) = o8;                 \
    }

#define COMPUTE_(buf)                                                                \
    {                                                                                \
        const char* Ab = lds + (buf) * 40960;                                        \
        const char* Bb = lds + (buf) * 40960 + 8192;                                 \
        _Pragma("unroll")                                                            \
        for (int ksub = 0; ksub < 2; ++ksub) {                                       \
            int cb_ = ksub * 64 + kq * 16;                                           \
            s16x8 a[2], bfr[4];                                                      \
            _Pragma("unroll")                                                        \
            for (int mf = 0; mf < 2; ++mf) {                                         \
                int pl_ = wm + mf * 16 + lm;                                         \
                a[mf] = *reinterpret_cast<const s16x8*>(                             \
                    Ab + pl_ * 128 + (cb_ ^ ((pl_ & 7) << 4)));                      \
            }                                                                        \
            _Pragma("unroll")                                                        \
            for (int nf = 0; nf < 4; ++nf) {                                         \
                int ol_ = wn + nf * 16 + lm;                                         \
                bfr[nf] = *reinterpret_cast<const s16x8*>(                           \
                    Bb + ol_ * 128 + (cb_ ^ ((ol_ & 7) << 4)));                      \
            }                                                                        \
            _Pragma("unroll")                                                        \
            for (int mf = 0; mf < 2; ++mf)                                           \
                _Pragma("unroll")                                                    \
                for (int nf = 0; nf < 4; ++nf)                                       \
                    acc[mf][nf] = __builtin_amdgcn_mfma_f32_16x16x32_bf16(           \
                        a[mf], bfr[nf], acc[mf][nf], 0, 0, 0);                       \
        }                                                                            \
    }

    STAGE_(0, 0);
    __syncthreads();

    int cur = 0;
#pragma unroll 1
    for (int t = 0; t < 36; ++t) {
        if (t < 35) STAGE_(t + 1, cur ^ 1);
        COMPUTE_(cur);
        __syncthreads();
        cur ^= 1;
    }
#undef STAGE_
#undef COMPUTE_

    // ---- epilogue: bias + store + GN partial ----
    float s = 0.f, sq = 0.f;
#pragma unroll
    for (int nf = 0; nf < 4; ++nf) {
        int oc = wn + nf * 16 + lm;
        float bv = bias[oc];
        float* orow = out + (b * CO_ + oc) * HW_ + hw0 + wm;
#pragma unroll
        for (int mf = 0; mf < 2; ++mf) {
            f32x4 r = acc[mf][nf];
            r.x += bv; r.y += bv; r.z += bv; r.w += bv;
            s  += r.x + r.y + r.z + r.w;
            sq += r.x * r.x + r.y * r.y + r.z * r.z + r.w * r.w;
            *reinterpret_cast<f32x4*>(orow + mf * 16 + kq * 4) = r;
        }
    }
#pragma unroll
    for (int o = 32; o > 0; o >>= 1) {
        s  += __shfl_down(s, o, 64);
        sq += __shfl_down(sq, o, 64);
    }
    if (lane == 0) { red[wv * 2] = s; red[wv * 2 + 1] = sq; }
    __syncthreads();
    if (tid == 0) {
        float S = 0.f, SQ = 0.f;
#pragma unroll
        for (int k = 0; k < 8; ++k) { S += red[k * 2]; SQ += red[k * 2 + 1]; }
        gnpart[blockIdx.x * 2]     = S;
        gnpart[blockIdx.x * 2 + 1] = SQ;
    }
}

// ---------------- K4: finalize stats. grid 4 (batch), 64 thr ----------------
// fused bid = pxt = b*64 + i
__global__ void k_gn_stats(const float* __restrict__ part, float* __restrict__ stats) {
    int b = blockIdx.x, t = threadIdx.x;
    float2 v = reinterpret_cast<const float2*>(part)[b * 64 + t];
    float s = v.x, sq = v.y;
#pragma unroll
    for (int o = 32; o > 0; o >>= 1) {
        s  += __shfl_down(s, o, 64);
        sq += __shfl_down(sq, o, 64);
    }
    if (t == 0) {
        const float n = (float)(CO_ * HW_);
        float mean = s / n;
        float var  = sq / n - mean * mean;
        stats[b * 2] = mean;
        stats[b * 2 + 1] = rsqrtf(var + GN_EPS_);
    }
}

// ---------------- K5: normalize + affine + relu ----------------
__global__ void k_gn_apply(float* __restrict__ y, const float* __restrict__ stats,
                           const float* __restrict__ gamma, const float* __restrict__ beta) {
    int e4 = blockIdx.x * 256 + threadIdx.x;
    int b  = e4 >> 18;
    int oc = (e4 >> 10) & 255;
    float mean = stats[b * 2], rstd = stats[b * 2 + 1];
    float g  = gamma[oc] * rstd;
    float bb = beta[oc] - mean * g;
    float4* p = reinterpret_cast<float4*>(y);
    float4 v = p[e4];
    v.x = fmaxf(v.x * g + bb, 0.f);
    v.y = fmaxf(v.y * g + bb, 0.f);
    v.z = fmaxf(v.z * g + bb, 0.f);
    v.w = fmaxf(v.w * g + bb, 0.f);
    p[e4] = v;
}

extern "C" void kernel_launch(void* const* d_in, const int* in_sizes, int n_in,
                              void* d_out, int out_size, void* d_ws, size_t ws_size,
                              hipStream_t stream) {
    const float* x     = (const float*)d_in[0];
    const float* w_off = (const float*)d_in[1];
    const float* b_off = (const float*)d_in[2];
    const float* w     = (const float*)d_in[3];
    const float* bias  = (const float*)d_in[4];
    const float* gamma = (const float*)d_in[5];
    const float* beta  = (const float*)d_in[6];
    float* out = (float*)d_out;

    // ws: [off 1.77MB][wT 1.18MB][wOffT 0.15MB][gnpart 2KB][stats][xT 8.4MB][offp 7.1MB]
    float* Wp     = (float*)d_ws;
    float* off    = Wp;                                 // 442368 floats
    short* wT     = (short*)(off + 27 * NPX_);          // 589824 shorts
    short* wOffT  = wT + 9 * 256 * 256;                 // 73728 shorts
    float* gnpart = (float*)(wOffT + 9 * 32 * 256);     // 512 floats
    float* stats  = gnpart + 512;                       // 8 floats
    short* xT     = (short*)(stats + 8);                // 4194304 shorts
    float* offp   = (float*)(xT + (long)NPX_ * 256);    // 4*27*NPX floats

    k_prep_w<<<256, 256, 0, stream>>>(w, wT);
    k_prep_woff<<<32, 256, 0, stream>>>(w_off, wOffT);
    k_xpose<<<1024, 256, 0, stream>>>(x, xT);
    k_offmfma<<<dim3(256, 4), 256, 0, stream>>>(xT, wOffT, offp);
    k_offreduce<<<1728, 256, 0, stream>>>(offp, b_off, off);
    k_fused<<<256, 512, 0, stream>>>(xT, off, wT, bias, out, gnpart);
    k_gn_stats<<<4, 64, 0, stream>>>(gnpart, stats);
    k_gn_apply<<<4096, 256, 0, stream>>>(out, stats, gamma, beta);
}